// Round 9
// baseline (185.906 us; speedup 1.0000x reference)
//
#include <hip/hip_runtime.h>

// GCN layer, bucket-binned pull aggregation (register accumulate, no float atomics,
// no global int atomics):
//   binning (bucket = row>>6): 3-pass chunked counting sort -> binned[] packed as
//     (row&63)<<26 | col; blkhist layout [chunk][bucket] (coalesced in histA/scatC)
//   degdis: one block per bucket, LDS histogram -> dis + lrp (row scan) for aggregate
//   zp[n] = bf16 pairs of dis[n]*(x@W^T), PADDED to 32 uints/row (128B aligned:
//     every gather row = exactly 2 cache lines; pad lanes read zeros, no guard)
//   aggregate: one block (512 thr) per bucket; LDS counting-sort by row (lrp
//     precomputed); full-64-lane pull-gather unroll-4, fused dis*acc+bias+ReLU.
// History: global atomics (R1 983us, R6 66us) and LDS float atomics (R4 499us) are
// dead ends; Ws stride 49 fixes 24-way bank conflict (R6: 156us->off top-5).

#define NF 48
#define NPAIR 24           // NF/2 valid uints per node row in zp
#define ZLD 32             // padded row stride in uints (128 B, aligned)
#define WS_LD 49           // padded leading dim for W in LDS (bank-conflict fix)
#define RB 64              // rows per bucket
#define CHUNK 8192         // edges per binning chunk (196 blocks -> good CU fill)
#define SCOL_CAP 2048      // per-bucket LDS col capacity (mean 1024, +32 sigma)

// zp[n*32+j] = bf16(dis[n]*(x@W^T)[2j]) | bf16(...[2j+1])<<16 ; j=24..31 -> 0
// block (32,8): j = threadIdx.x, n = blockIdx.x*8 + threadIdx.y
__global__ void transform_kernel(const float* __restrict__ x, const float* __restrict__ W,
                                 const float* __restrict__ dis, unsigned* __restrict__ zp, int N) {
    __shared__ float Ws[NF * WS_LD];
    int tid = threadIdx.y * 32 + threadIdx.x;
    for (int i = tid; i < NF * NF; i += 256)
        Ws[(i / NF) * WS_LD + (i % NF)] = W[i];
    __syncthreads();
    int n = blockIdx.x * 8 + threadIdx.y;
    int j = threadIdx.x;
    if (n >= N) return;
    if (j >= NPAIR) {                    // zero the pad lanes
        zp[(size_t)n * ZLD + j] = 0u;
        return;
    }
    const float* xr = x + (size_t)n * NF;
    const float* w0 = Ws + (2 * j) * WS_LD;
    const float* w1 = Ws + (2 * j + 1) * WS_LD;
    float s0 = 0.0f, s1 = 0.0f;
#pragma unroll
    for (int k = 0; k < NF; k++) {
        float xv = xr[k];
        s0 = fmaf(xv, w0[k], s0);
        s1 = fmaf(xv, w1[k], s1);
    }
    float d = dis[n];
    s0 *= d; s1 *= d;
    unsigned u0 = __float_as_uint(s0);
    unsigned u1 = __float_as_uint(s1);
    u0 = (u0 + 0x7fffu + ((u0 >> 16) & 1u)) >> 16;
    u1 = (u1 + 0x7fffu + ((u1 >> 16) & 1u)) >> 16;
    zp[(size_t)n * ZLD + j] = u0 | (u1 << 16);
}

// Pass A: per-chunk bucket histogram; blkhist[chunk][bucket] (coalesced store)
__global__ void histA_kernel(const int* __restrict__ row, int* __restrict__ blkhist,
                             int NBUK, int E) {
    extern __shared__ int hist[];       // NBUK ints
    for (int i = threadIdx.x; i < NBUK; i += blockDim.x) hist[i] = 0;
    __syncthreads();
    int b = blockIdx.x;
    int s = b * CHUNK, t = min(E, s + CHUNK);
    int nv = (t - s) >> 2;              // int4 groups
    const int4* r4 = (const int4*)(row + s);
    for (int i = threadIdx.x; i < nv; i += blockDim.x) {
        int4 r = r4[i];
        atomicAdd(&hist[r.x >> 6], 1);
        atomicAdd(&hist[r.y >> 6], 1);
        atomicAdd(&hist[r.z >> 6], 1);
        atomicAdd(&hist[r.w >> 6], 1);
    }
    for (int e = s + nv * 4 + threadIdx.x; e < t; e += blockDim.x)
        atomicAdd(&hist[row[e] >> 6], 1);
    __syncthreads();
    int* dst = blkhist + (size_t)b * NBUK;
    for (int k = threadIdx.x; k < NBUK; k += blockDim.x) dst[k] = hist[k];
}

// Pass B1: per bucket, exclusive scan over chunks (in place, strided) + total
__global__ void scanB1_kernel(int* __restrict__ blkhist, int* __restrict__ btotal,
                              int NBUK, int NCH) {
    int k = blockIdx.x;
    int lane = threadIdx.x;             // blockDim.x == 64
    int carry = 0;
    for (int base = 0; base < NCH; base += 64) {
        int i = base + lane;
        int v = (i < NCH) ? blkhist[(size_t)i * NBUK + k] : 0;
        int incl = v;
        #pragma unroll
        for (int off = 1; off < 64; off <<= 1) {
            int u = __shfl_up(incl, off, 64);
            if (lane >= off) incl += u;
        }
        if (i < NCH) blkhist[(size_t)i * NBUK + k] = carry + incl - v;
        carry += __shfl(incl, 63, 64);
    }
    if (lane == 0) btotal[k] = carry;
}

// Pass B2: single-block exclusive scan of bucket totals -> bbase
__global__ void scanB2_kernel(const int* __restrict__ btotal, int* __restrict__ bbase,
                              int NBUK, int E) {
    __shared__ int wsum[8];
    __shared__ int carry_s;
    if (threadIdx.x == 0) carry_s = 0;
    __syncthreads();
    const int lane = threadIdx.x & 63;
    const int wave = threadIdx.x >> 6;  // blockDim.x == 512
    for (int base = 0; base < NBUK; base += 512) {
        int i = base + threadIdx.x;
        int v = (i < NBUK) ? btotal[i] : 0;
        int incl = v;
        #pragma unroll
        for (int off = 1; off < 64; off <<= 1) {
            int u = __shfl_up(incl, off, 64);
            if (lane >= off) incl += u;
        }
        if (lane == 63) wsum[wave] = incl;
        __syncthreads();
        int woff = 0;
        #pragma unroll
        for (int w = 0; w < 8; w++) if (w < wave) woff += wsum[w];
        if (i < NBUK) bbase[i] = carry_s + woff + (incl - v);
        __syncthreads();
        if (threadIdx.x == 511) carry_s += woff + incl;
        __syncthreads();
    }
    if (threadIdx.x == 0) bbase[NBUK] = E;
}

// Pass C: scatter edges to bucket-grouped binned[], packed (row&63)<<26 | col
__global__ void scatC_kernel(const int* __restrict__ row, const int* __restrict__ col,
                             const int* __restrict__ blkhist, const int* __restrict__ bbase,
                             unsigned* __restrict__ binned, int NBUK, int E) {
    extern __shared__ int cur[];        // NBUK ints
    int b = blockIdx.x;
    const int* boff = blkhist + (size_t)b * NBUK;
    for (int k = threadIdx.x; k < NBUK; k += blockDim.x)
        cur[k] = bbase[k] + boff[k];    // coalesced
    __syncthreads();
    int s = b * CHUNK, t = min(E, s + CHUNK);
    int nv = (t - s) >> 2;
    const int4* r4 = (const int4*)(row + s);
    const int4* c4 = (const int4*)(col + s);
    for (int i = threadIdx.x; i < nv; i += blockDim.x) {
        int4 r = r4[i];
        int4 c = c4[i];
        int p0 = atomicAdd(&cur[r.x >> 6], 1);
        binned[p0] = ((unsigned)(r.x & (RB - 1)) << 26) | (unsigned)c.x;
        int p1 = atomicAdd(&cur[r.y >> 6], 1);
        binned[p1] = ((unsigned)(r.y & (RB - 1)) << 26) | (unsigned)c.y;
        int p2 = atomicAdd(&cur[r.z >> 6], 1);
        binned[p2] = ((unsigned)(r.z & (RB - 1)) << 26) | (unsigned)c.z;
        int p3 = atomicAdd(&cur[r.w >> 6], 1);
        binned[p3] = ((unsigned)(r.w & (RB - 1)) << 26) | (unsigned)c.w;
    }
    for (int e = s + nv * 4 + threadIdx.x; e < t; e += blockDim.x) {
        int r = row[e], c = col[e];
        int pos = atomicAdd(&cur[r >> 6], 1);
        binned[pos] = ((unsigned)(r & (RB - 1)) << 26) | (unsigned)c;
    }
}

// One block per bucket: LDS histogram of row&63 -> dis + per-bucket row scan (lrp_g).
__global__ void degdis_kernel(const int* __restrict__ bbase, const unsigned* __restrict__ binned,
                              float* __restrict__ dis, int* __restrict__ lrp_g, int N) {
    __shared__ int hist[RB];
    const int b = blockIdx.x;
    const int s = bbase[b];
    const int t = bbase[b + 1];
    const int tid = threadIdx.x;
    if (tid < RB) hist[tid] = 0;
    __syncthreads();
    for (int e = s + tid; e < t; e += 512)
        atomicAdd(&hist[binned[e] >> 26], 1);
    __syncthreads();
    if (tid < RB) {
        int v = hist[tid];
        int incl = v;
        #pragma unroll
        for (int off = 1; off < 64; off <<= 1) {
            int u = __shfl_up(incl, off, 64);
            if (tid >= off) incl += u;
        }
        int* lp = lrp_g + (size_t)b * (RB + 1);
        lp[tid] = incl - v;
        if (tid == RB - 1) lp[RB] = incl;
        int n = b * RB + tid;
        if (n < N) dis[n] = (v > 0) ? rsqrtf((float)v) : 0.0f;
    }
}

// One block (512 thr) per bucket: LDS counting sort by row, full-lane unroll-4 gather.
__global__ __launch_bounds__(512, 8)
void aggregate_kernel(const int* __restrict__ bbase, const unsigned* __restrict__ binned,
                      const int* __restrict__ lrp_g,
                      const unsigned* __restrict__ zp, const float* __restrict__ dis,
                      const float* __restrict__ bias, float* __restrict__ out, int N) {
    __shared__ int scol[SCOL_CAP];
    __shared__ int lrp[RB + 1];
    __shared__ int cur[RB];
    const int b = blockIdx.x;
    const int s = bbase[b];
    const int t = bbase[b + 1];
    const int cnt = t - s;
    const int tid = threadIdx.x;
    if (tid < RB + 1) {
        int v = lrp_g[(size_t)b * (RB + 1) + tid];
        lrp[tid] = v;
        if (tid < RB) cur[tid] = v;
    }
    __syncthreads();
    const bool sorted = (cnt <= SCOL_CAP);
    if (sorted) {
        for (int e = s + tid; e < t; e += 512) {
            unsigned rc = binned[e];
            int pos = atomicAdd(&cur[rc >> 26], 1);
            scol[pos] = (int)(rc & 0x3ffffffu);
        }
    }
    __syncthreads();

    const int lane = tid & 63;
    const int wave = tid >> 6;           // 0..7
    const int h = lane >> 5;             // half-wave: edge parity
    const int j = lane & 31;             // feature-pair index (24..31 = pad, reads 0s)
    const bool act = (j < NPAIR);
    float bb0 = 0.0f, bb1 = 0.0f;
    if (act) { bb0 = bias[2 * j]; bb1 = bias[2 * j + 1]; }
    const int rbase = b * RB;
    for (int ri = wave; ri < RB; ri += 8) {
        int r = rbase + ri;
        if (r >= N) break;
        float a0 = 0.0f, a1 = 0.0f;
        if (sorted) {
            int ks = lrp[ri], ke = lrp[ri + 1];
            int k = ks + h;
            for (; k + 6 < ke; k += 8) {     // unroll 4: edges k,k+2,k+4,k+6 of parity
                int c0 = scol[k];
                int c1 = scol[k + 2];
                int c2 = scol[k + 4];
                int c3 = scol[k + 6];
                unsigned u0 = zp[((size_t)c0 << 5) + j];   // aligned 2-line rows
                unsigned u1 = zp[((size_t)c1 << 5) + j];
                unsigned u2 = zp[((size_t)c2 << 5) + j];
                unsigned u3 = zp[((size_t)c3 << 5) + j];
                a0 += (__uint_as_float(u0 << 16) + __uint_as_float(u1 << 16)) +
                      (__uint_as_float(u2 << 16) + __uint_as_float(u3 << 16));
                a1 += (__uint_as_float(u0 & 0xffff0000u) + __uint_as_float(u1 & 0xffff0000u)) +
                      (__uint_as_float(u2 & 0xffff0000u) + __uint_as_float(u3 & 0xffff0000u));
            }
            for (; k < ke; k += 2) {
                int c0 = scol[k];
                unsigned u0 = zp[((size_t)c0 << 5) + j];
                a0 += __uint_as_float(u0 << 16);
                a1 += __uint_as_float(u0 & 0xffff0000u);
            }
        } else {                         // overflow fallback (statistically unreachable)
            for (int e = s; e < t; e++) {
                unsigned rc = binned[e];
                if ((int)(rc >> 26) == ri && h == 0 && act) {
                    unsigned u0 = zp[((size_t)(rc & 0x3ffffffu) << 5) + j];
                    a0 += __uint_as_float(u0 << 16);
                    a1 += __uint_as_float(u0 & 0xffff0000u);
                }
            }
        }
        a0 += __shfl_xor(a0, 32, 64);    // combine edge parities
        a1 += __shfl_xor(a1, 32, 64);
        if (h == 0 && act) {
            float dr = dis[r];
            float v0 = dr * a0 + bb0;
            float v1 = dr * a1 + bb1;
            float2 o;
            o.x = v0 > 0.0f ? v0 : 0.0f;
            o.y = v1 > 0.0f ? v1 : 0.0f;
            *(float2*)(out + (size_t)r * NF + 2 * j) = o;
        }
    }
}

extern "C" void kernel_launch(void* const* d_in, const int* in_sizes, int n_in,
                              void* d_out, int out_size, void* d_ws, size_t ws_size,
                              hipStream_t stream) {
    const float* x    = (const float*)d_in[0];
    const int*   ei   = (const int*)d_in[1];
    const float* W    = (const float*)d_in[2];
    const float* bias = (const float*)d_in[3];
    float* out = (float*)d_out;

    const int N = in_sizes[0] / NF;
    const int E = in_sizes[1] / 2;
    const int* row = ei;                      // edge_index[0]
    const int* col = ei + E;                  // edge_index[1]
    const int NBUK = (N + RB - 1) / RB;       // 1563
    const int NCH  = (E + CHUNK - 1) / CHUNK; // 196

    // workspace layout
    char* ws = (char*)d_ws;
    unsigned* zp      = (unsigned*)ws;       ws += (size_t)N * ZLD * 4;          // 12.8 MB
    unsigned* binned  = (unsigned*)ws;       ws += (size_t)E * 4;                // 6.4 MB
    float*    dis     = (float*)ws;          ws += (size_t)N * 4;
    int*      blkhist = (int*)ws;            ws += (size_t)NCH * NBUK * 4;       // 1.2 MB
    int*      btotal  = (int*)ws;            ws += (size_t)NBUK * 4;
    int*      bbase   = (int*)ws;            ws += (size_t)(NBUK + 1) * 4;
    int*      lrp_g   = (int*)ws;            ws += (size_t)NBUK * (RB + 1) * 4;  // 406 KB

    histA_kernel<<<NCH, 512, NBUK * 4, stream>>>(row, blkhist, NBUK, E);
    scanB1_kernel<<<NBUK, 64, 0, stream>>>(blkhist, btotal, NBUK, NCH);
    scanB2_kernel<<<1, 512, 0, stream>>>(btotal, bbase, NBUK, E);
    scatC_kernel<<<NCH, 512, NBUK * 4, stream>>>(row, col, blkhist, bbase, binned, NBUK, E);
    degdis_kernel<<<NBUK, 512, 0, stream>>>(bbase, binned, dis, lrp_g, N);
    dim3 tb(32, 8);
    transform_kernel<<<(N + 7) / 8, tb, 0, stream>>>(x, W, dis, zp, N);
    aggregate_kernel<<<NBUK, 512, 0, stream>>>(bbase, binned, lrp_g, zp, dis, bias, out, N);
}

// Round 12
// 159.350 us; speedup vs baseline: 1.1667x; 1.1667x over previous
//
#include <hip/hip_runtime.h>

// GCN layer, bucket-binned pull aggregation (register accumulate, no float atomics,
// no global int atomics):
//   binning (bucket = row>>6): 3-pass chunked counting sort -> binned[] packed as
//     (row&63)<<26 | col; blkhist layout [chunk][bucket] (coalesced in histA/scatC)
//   degdis: one block per bucket, LDS histogram -> dis + lrp (row scan) for aggregate
//   transform: MFMA bf16 GEMM (x,W -> bf16; 16x16x32, K 48 padded to 64); writes
//     zp rows of 64 bf16 (128 B aligned; features 48..63 zero-padded)
//   aggregate: one block (512 thr) per bucket; LDS counting-sort by row (lrp
//     precomputed); full-64-lane pull-gather unroll-4, fused dis*acc+bias+ReLU.
// History: global atomics (R1 983us, R6 66us) and LDS float atomics (R4 499us) are
// dead ends; Ws-stride-49 FMA transform was LDS-issue bound at ~45us (R9) -> MFMA.
// R10/R11 benches were container-level infra failures; identical resubmit (audit
// found no OOB/fault path in the MFMA transform).

#define NF 48
#define NPAIR 24           // NF/2 valid uints per node row in zp
#define ZLD 32             // zp row stride in uints (128 B aligned)
#define RB 64              // rows per bucket
#define CHUNK 16384        // edges per binning chunk (98 chunks; longer scatter runs)
#define SCOL_CAP 2048      // per-bucket LDS col capacity (mean 1024, +32 sigma)

typedef __attribute__((ext_vector_type(8))) short frag_ab;   // 8 bf16
typedef __attribute__((ext_vector_type(4))) float f32x4;

__device__ inline unsigned short f2bf(float f) {
    unsigned u = __float_as_uint(f);
    u = (u + 0x7fffu + ((u >> 16) & 1u)) >> 16;   // RN-even
    return (unsigned short)u;
}

// MFMA transform: zp16[n*64 + f] = bf16( dis[n] * (x[n] @ W^T)[f] ), f=48..63 -> 0
// Block: 256 thr (4 waves), 64 nodes; wave w handles nodes [w*16, w*16+16).
__global__ void transform_kernel(const float* __restrict__ x, const float* __restrict__ W,
                                 const float* __restrict__ dis,
                                 unsigned short* __restrict__ zp16, int N) {
    __shared__ unsigned short Xb[64 * 64];   // 8 KB, row stride 64 (K padded)
    __shared__ unsigned short Wb[48 * 64];   // 6 KB, [out][in] = B[k][n] source
    const int tid = threadIdx.x;
    const int nb0 = blockIdx.x * 64;

    // stage x -> Xb (bf16), 768 float4s
    const float4* x4 = (const float4*)x;
    for (int i = tid; i < 768; i += 256) {
        int r = i / 12, c = i % 12;
        int n = nb0 + r;
        float4 v = (n < N) ? x4[(size_t)n * 12 + c] : make_float4(0.f, 0.f, 0.f, 0.f);
        unsigned short* d = &Xb[r * 64 + c * 4];
        d[0] = f2bf(v.x); d[1] = f2bf(v.y); d[2] = f2bf(v.z); d[3] = f2bf(v.w);
    }
    // zero Xb K-pad (cols 48..63): rows*8 uints
    for (int i = tid; i < 64 * 8; i += 256)
        ((unsigned*)Xb)[(i >> 3) * 32 + 24 + (i & 7)] = 0u;
    // stage W -> Wb (bf16), 576 float4s
    const float4* W4 = (const float4*)W;
    for (int i = tid; i < 576; i += 256) {
        int r = i / 12, c = i % 12;
        float4 v = W4[r * 12 + c];
        unsigned short* d = &Wb[r * 64 + c * 4];
        d[0] = f2bf(v.x); d[1] = f2bf(v.y); d[2] = f2bf(v.z); d[3] = f2bf(v.w);
    }
    for (int i = tid; i < 48 * 8; i += 256)
        ((unsigned*)Wb)[(i >> 3) * 32 + 24 + (i & 7)] = 0u;
    __syncthreads();

    const int wv = tid >> 6, lane = tid & 63;
    const int quad = lane >> 4, l16 = lane & 15;
    const int mrow = wv * 16 + l16;

    frag_ab A0 = *(const frag_ab*)&Xb[mrow * 64 + quad * 8];
    frag_ab A1 = *(const frag_ab*)&Xb[mrow * 64 + 32 + quad * 8];
    f32x4 acc[3];
#pragma unroll
    for (int t = 0; t < 3; t++) {
        frag_ab B0 = *(const frag_ab*)&Wb[(t * 16 + l16) * 64 + quad * 8];
        frag_ab B1 = *(const frag_ab*)&Wb[(t * 16 + l16) * 64 + 32 + quad * 8];
        f32x4 z = {0.f, 0.f, 0.f, 0.f};
        z = __builtin_amdgcn_mfma_f32_16x16x32_bf16(A0, B0, z, 0, 0, 0);
        z = __builtin_amdgcn_mfma_f32_16x16x32_bf16(A1, B1, z, 0, 0, 0);
        acc[t] = z;
    }
    // D mapping: col = lane&15 (feature within tile), row = quad*4 + r (node)
#pragma unroll
    for (int r = 0; r < 4; r++) {
        int n = nb0 + wv * 16 + quad * 4 + r;
        if (n < N) {
            float dn = dis[n];
            unsigned short* zr = zp16 + (size_t)n * 64;
#pragma unroll
            for (int t = 0; t < 3; t++)
                zr[t * 16 + l16] = f2bf(dn * acc[t][r]);
            zr[48 + l16] = 0;            // feature pad
        }
    }
}

// Pass A: per-chunk bucket histogram; blkhist[chunk][bucket] (coalesced store)
__global__ void histA_kernel(const int* __restrict__ row, int* __restrict__ blkhist,
                             int NBUK, int E) {
    extern __shared__ int hist[];       // NBUK ints
    for (int i = threadIdx.x; i < NBUK; i += blockDim.x) hist[i] = 0;
    __syncthreads();
    int b = blockIdx.x;
    int s = b * CHUNK, t = min(E, s + CHUNK);
    int nv = (t - s) >> 2;              // int4 groups
    const int4* r4 = (const int4*)(row + s);
    for (int i = threadIdx.x; i < nv; i += blockDim.x) {
        int4 r = r4[i];
        atomicAdd(&hist[r.x >> 6], 1);
        atomicAdd(&hist[r.y >> 6], 1);
        atomicAdd(&hist[r.z >> 6], 1);
        atomicAdd(&hist[r.w >> 6], 1);
    }
    for (int e = s + nv * 4 + threadIdx.x; e < t; e += blockDim.x)
        atomicAdd(&hist[row[e] >> 6], 1);
    __syncthreads();
    int* dst = blkhist + (size_t)b * NBUK;
    for (int k = threadIdx.x; k < NBUK; k += blockDim.x) dst[k] = hist[k];
}

// Pass B1: per bucket, exclusive scan over chunks (in place, strided) + total
__global__ void scanB1_kernel(int* __restrict__ blkhist, int* __restrict__ btotal,
                              int NBUK, int NCH) {
    int k = blockIdx.x;
    int lane = threadIdx.x;             // blockDim.x == 64
    int carry = 0;
    for (int base = 0; base < NCH; base += 64) {
        int i = base + lane;
        int v = (i < NCH) ? blkhist[(size_t)i * NBUK + k] : 0;
        int incl = v;
        #pragma unroll
        for (int off = 1; off < 64; off <<= 1) {
            int u = __shfl_up(incl, off, 64);
            if (lane >= off) incl += u;
        }
        if (i < NCH) blkhist[(size_t)i * NBUK + k] = carry + incl - v;
        carry += __shfl(incl, 63, 64);
    }
    if (lane == 0) btotal[k] = carry;
}

// Pass B2: single-block exclusive scan of bucket totals -> bbase
__global__ void scanB2_kernel(const int* __restrict__ btotal, int* __restrict__ bbase,
                              int NBUK, int E) {
    __shared__ int wsum[8];
    __shared__ int carry_s;
    if (threadIdx.x == 0) carry_s = 0;
    __syncthreads();
    const int lane = threadIdx.x & 63;
    const int wave = threadIdx.x >> 6;  // blockDim.x == 512
    for (int base = 0; base < NBUK; base += 512) {
        int i = base + threadIdx.x;
        int v = (i < NBUK) ? btotal[i] : 0;
        int incl = v;
        #pragma unroll
        for (int off = 1; off < 64; off <<= 1) {
            int u = __shfl_up(incl, off, 64);
            if (lane >= off) incl += u;
        }
        if (lane == 63) wsum[wave] = incl;
        __syncthreads();
        int woff = 0;
        #pragma unroll
        for (int w = 0; w < 8; w++) if (w < wave) woff += wsum[w];
        if (i < NBUK) bbase[i] = carry_s + woff + (incl - v);
        __syncthreads();
        if (threadIdx.x == 511) carry_s += woff + incl;
        __syncthreads();
    }
    if (threadIdx.x == 0) bbase[NBUK] = E;
}

// Pass C: scatter edges to bucket-grouped binned[], packed (row&63)<<26 | col
__global__ void scatC_kernel(const int* __restrict__ row, const int* __restrict__ col,
                             const int* __restrict__ blkhist, const int* __restrict__ bbase,
                             unsigned* __restrict__ binned, int NBUK, int E) {
    extern __shared__ int cur[];        // NBUK ints
    int b = blockIdx.x;
    const int* boff = blkhist + (size_t)b * NBUK;
    for (int k = threadIdx.x; k < NBUK; k += blockDim.x)
        cur[k] = bbase[k] + boff[k];    // coalesced
    __syncthreads();
    int s = b * CHUNK, t = min(E, s + CHUNK);
    int nv = (t - s) >> 2;
    const int4* r4 = (const int4*)(row + s);
    const int4* c4 = (const int4*)(col + s);
    for (int i = threadIdx.x; i < nv; i += blockDim.x) {
        int4 r = r4[i];
        int4 c = c4[i];
        int p0 = atomicAdd(&cur[r.x >> 6], 1);
        binned[p0] = ((unsigned)(r.x & (RB - 1)) << 26) | (unsigned)c.x;
        int p1 = atomicAdd(&cur[r.y >> 6], 1);
        binned[p1] = ((unsigned)(r.y & (RB - 1)) << 26) | (unsigned)c.y;
        int p2 = atomicAdd(&cur[r.z >> 6], 1);
        binned[p2] = ((unsigned)(r.z & (RB - 1)) << 26) | (unsigned)c.z;
        int p3 = atomicAdd(&cur[r.w >> 6], 1);
        binned[p3] = ((unsigned)(r.w & (RB - 1)) << 26) | (unsigned)c.w;
    }
    for (int e = s + nv * 4 + threadIdx.x; e < t; e += blockDim.x) {
        int r = row[e], c = col[e];
        int pos = atomicAdd(&cur[r >> 6], 1);
        binned[pos] = ((unsigned)(r & (RB - 1)) << 26) | (unsigned)c;
    }
}

// One block per bucket: LDS histogram of row&63 -> dis + per-bucket row scan (lrp_g).
__global__ void degdis_kernel(const int* __restrict__ bbase, const unsigned* __restrict__ binned,
                              float* __restrict__ dis, int* __restrict__ lrp_g, int N) {
    __shared__ int hist[RB];
    const int b = blockIdx.x;
    const int s = bbase[b];
    const int t = bbase[b + 1];
    const int tid = threadIdx.x;
    if (tid < RB) hist[tid] = 0;
    __syncthreads();
    for (int e = s + tid; e < t; e += 512)
        atomicAdd(&hist[binned[e] >> 26], 1);
    __syncthreads();
    if (tid < RB) {
        int v = hist[tid];
        int incl = v;
        #pragma unroll
        for (int off = 1; off < 64; off <<= 1) {
            int u = __shfl_up(incl, off, 64);
            if (tid >= off) incl += u;
        }
        int* lp = lrp_g + (size_t)b * (RB + 1);
        lp[tid] = incl - v;
        if (tid == RB - 1) lp[RB] = incl;
        int n = b * RB + tid;
        if (n < N) dis[n] = (v > 0) ? rsqrtf((float)v) : 0.0f;
    }
}

// One block (512 thr) per bucket: LDS counting sort by row, full-lane unroll-4 gather.
__global__ __launch_bounds__(512, 8)
void aggregate_kernel(const int* __restrict__ bbase, const unsigned* __restrict__ binned,
                      const int* __restrict__ lrp_g,
                      const unsigned* __restrict__ zp, const float* __restrict__ dis,
                      const float* __restrict__ bias, float* __restrict__ out, int N) {
    __shared__ int scol[SCOL_CAP];
    __shared__ int lrp[RB + 1];
    __shared__ int cur[RB];
    const int b = blockIdx.x;
    const int s = bbase[b];
    const int t = bbase[b + 1];
    const int cnt = t - s;
    const int tid = threadIdx.x;
    if (tid < RB + 1) {
        int v = lrp_g[(size_t)b * (RB + 1) + tid];
        lrp[tid] = v;
        if (tid < RB) cur[tid] = v;
    }
    __syncthreads();
    const bool sorted = (cnt <= SCOL_CAP);
    if (sorted) {
        for (int e = s + tid; e < t; e += 512) {
            unsigned rc = binned[e];
            int pos = atomicAdd(&cur[rc >> 26], 1);
            scol[pos] = (int)(rc & 0x3ffffffu);
        }
    }
    __syncthreads();

    const int lane = tid & 63;
    const int wave = tid >> 6;           // 0..7
    const int h = lane >> 5;             // half-wave: edge parity
    const int j = lane & 31;             // feature-pair index (24..31 = pad, reads 0s)
    const bool act = (j < NPAIR);
    float bb0 = 0.0f, bb1 = 0.0f;
    if (act) { bb0 = bias[2 * j]; bb1 = bias[2 * j + 1]; }
    const int rbase = b * RB;
    for (int ri = wave; ri < RB; ri += 8) {
        int r = rbase + ri;
        if (r >= N) break;
        float a0 = 0.0f, a1 = 0.0f;
        if (sorted) {
            int ks = lrp[ri], ke = lrp[ri + 1];
            int k = ks + h;
            for (; k + 6 < ke; k += 8) {     // unroll 4: edges k,k+2,k+4,k+6 of parity
                int c0 = scol[k];
                int c1 = scol[k + 2];
                int c2 = scol[k + 4];
                int c3 = scol[k + 6];
                unsigned u0 = zp[((size_t)c0 << 5) + j];   // aligned 2-line rows
                unsigned u1 = zp[((size_t)c1 << 5) + j];
                unsigned u2 = zp[((size_t)c2 << 5) + j];
                unsigned u3 = zp[((size_t)c3 << 5) + j];
                a0 += (__uint_as_float(u0 << 16) + __uint_as_float(u1 << 16)) +
                      (__uint_as_float(u2 << 16) + __uint_as_float(u3 << 16));
                a1 += (__uint_as_float(u0 & 0xffff0000u) + __uint_as_float(u1 & 0xffff0000u)) +
                      (__uint_as_float(u2 & 0xffff0000u) + __uint_as_float(u3 & 0xffff0000u));
            }
            for (; k < ke; k += 2) {
                int c0 = scol[k];
                unsigned u0 = zp[((size_t)c0 << 5) + j];
                a0 += __uint_as_float(u0 << 16);
                a1 += __uint_as_float(u0 & 0xffff0000u);
            }
        } else {                         // overflow fallback (statistically unreachable)
            for (int e = s; e < t; e++) {
                unsigned rc = binned[e];
                if ((int)(rc >> 26) == ri && h == 0 && act) {
                    unsigned u0 = zp[((size_t)(rc & 0x3ffffffu) << 5) + j];
                    a0 += __uint_as_float(u0 << 16);
                    a1 += __uint_as_float(u0 & 0xffff0000u);
                }
            }
        }
        a0 += __shfl_xor(a0, 32, 64);    // combine edge parities
        a1 += __shfl_xor(a1, 32, 64);
        if (h == 0 && act) {
            float dr = dis[r];
            float v0 = dr * a0 + bb0;
            float v1 = dr * a1 + bb1;
            float2 o;
            o.x = v0 > 0.0f ? v0 : 0.0f;
            o.y = v1 > 0.0f ? v1 : 0.0f;
            *(float2*)(out + (size_t)r * NF + 2 * j) = o;
        }
    }
}

extern "C" void kernel_launch(void* const* d_in, const int* in_sizes, int n_in,
                              void* d_out, int out_size, void* d_ws, size_t ws_size,
                              hipStream_t stream) {
    const float* x    = (const float*)d_in[0];
    const int*   ei   = (const int*)d_in[1];
    const float* W    = (const float*)d_in[2];
    const float* bias = (const float*)d_in[3];
    float* out = (float*)d_out;

    const int N = in_sizes[0] / NF;
    const int E = in_sizes[1] / 2;
    const int* row = ei;                      // edge_index[0]
    const int* col = ei + E;                  // edge_index[1]
    const int NBUK = (N + RB - 1) / RB;       // 1563
    const int NCH  = (E + CHUNK - 1) / CHUNK; // 98

    // workspace layout
    char* ws = (char*)d_ws;
    unsigned* zp      = (unsigned*)ws;       ws += (size_t)N * ZLD * 4;          // 12.8 MB
    unsigned* binned  = (unsigned*)ws;       ws += (size_t)E * 4;                // 6.4 MB
    float*    dis     = (float*)ws;          ws += (size_t)N * 4;
    int*      blkhist = (int*)ws;            ws += (size_t)NCH * NBUK * 4;       // 612 KB
    int*      btotal  = (int*)ws;            ws += (size_t)NBUK * 4;
    int*      bbase   = (int*)ws;            ws += (size_t)(NBUK + 1) * 4;
    int*      lrp_g   = (int*)ws;            ws += (size_t)NBUK * (RB + 1) * 4;  // 406 KB

    histA_kernel<<<NCH, 512, NBUK * 4, stream>>>(row, blkhist, NBUK, E);
    scanB1_kernel<<<NBUK, 64, 0, stream>>>(blkhist, btotal, NBUK, NCH);
    scanB2_kernel<<<1, 512, 0, stream>>>(btotal, bbase, NBUK, E);
    scatC_kernel<<<NCH, 512, NBUK * 4, stream>>>(row, col, blkhist, bbase, binned, NBUK, E);
    degdis_kernel<<<NBUK, 512, 0, stream>>>(bbase, binned, dis, lrp_g, N);
    transform_kernel<<<(N + 63) / 64, 256, 0, stream>>>(x, W, dis, (unsigned short*)zp, N);
    aggregate_kernel<<<NBUK, 512, 0, stream>>>(bbase, binned, lrp_g, zp, dis, bias, out, N);
}